// Round 13
// baseline (920.285 us; speedup 1.0000x reference)
//
#include <hip/hip_runtime.h>
#include <stdint.h>
#include <math.h>

// Round 19.
// r18 counters: fold 406us, FETCH 266MB (L2-resident geometry confirmed),
// VALUBusy 21.6%, hbm 17% -> latency-bound at 7.9 cyc/gather: each 4-entry
// chunk serially exposes s_load(200cy) -> addr -> global_load(200cy) -> fma.
// fold v8: software-pipeline the pair stream. pairsA stride 68 (prefetch
// guard); per chunk, prefetch next chunk's pairs (4x s_load_dwordx8 into
// SGPRs) WHILE issuing current chunk's 16 gathers+fmas. Steady state: one
// chunk of s_loads + one chunk of v_loads in flight per wave; 4 waves/SIMD
// share gather latency.
// select v5.1 BYTE-IDENTICAL (3rd attempt to get its counters: stable
// ~380-400us across variants, 2.5x over traffic+VALU model; with fold
// ~250us it must land in top-5).
// Numerics unchanged (validated): ascending-k f32 fmaf fold from +0
// (zero-pad exact no-op), +bias, *boost, monotone-u32 key, ties >=.

#define BATCH 16384
#define K_DIM 512
#define N_DIM 4096
#define MAXE 64
#define PSTR 68      // pair stride: 64 + 4-entry prefetch guard
#define ROWS_A 64

typedef float f32x4 __attribute__((ext_vector_type(4)));
typedef unsigned int u32;
typedef struct { uint2 e[4]; } chunk4;   // 32B -> s_load_dwordx8

// ---------- boost table ----------
__global__ void boost_kernel(const float* __restrict__ duty,
                             const int* __restrict__ kptr,
                             float* __restrict__ boost) {
  const int j = blockIdx.x * blockDim.x + threadIdx.x;
  if (j < N_DIM) {
    const float td = (float)((double)kptr[0] / (double)N_DIM);
    const float arg = 0.5f * (td - duty[j]);      // f32 ops, as reference
    boost[j] = (float)exp((double)arg);           // correctly-rounded f32 exp
  }
}

// ---------- compress: per-column nonzeros, ascending k ----------
__global__ __launch_bounds__(256) void compress_kernel(
    const float* __restrict__ W, const float* __restrict__ mask,
    unsigned short* __restrict__ cIdx, float* __restrict__ cVal,
    int* __restrict__ cnt) {
  const int j = blockIdx.x * 4 + (threadIdx.x >> 6);  // one wave per column
  const int lane = threadIdx.x & 63;
  if (j >= N_DIM) return;
  const float* mr = mask + (size_t)j * K_DIM;
  const float* wr = W + (size_t)j * K_DIM;
  int base = 0;
#pragma unroll
  for (int c = 0; c < K_DIM / 64; ++c) {
    const int k = c * 64 + lane;
    const bool act = (mr[k] != 0.0f);
    const unsigned long long bal = __ballot(act);
    const int pos = __popcll(bal & ((1ull << lane) - 1ull));
    if (act && base + pos < MAXE) {
      cIdx[(size_t)j * MAXE + base + pos] = (unsigned short)k;
      cVal[(size_t)j * MAXE + base + pos] = wr[k];   // mask==1 -> exact
    }
    base += (int)__popcll(bal);
  }
  if (lane == 0) cnt[j] = base < MAXE ? base : MAXE;
}

// ---------- per-4-col max count, rounded up to 4 ----------
__global__ __launch_bounds__(256) void cmax_kernel(
    const int* __restrict__ cnt, int* __restrict__ cm4) {
  const int i = blockIdx.x * 256 + threadIdx.x;    // 0..1023
  const int4 c = *(const int4*)(cnt + i * 4);
  int m = c.x > c.y ? c.x : c.y;
  m = c.z > m ? c.z : m;
  m = c.w > m ? c.w : m;
  cm4[i] = (m + 3) & ~3;
}

// ---------- pack (xTg byte-offset, w-bits) pairs, stride 68 ----------
__global__ __launch_bounds__(256) void fillA_kernel(
    const unsigned short* __restrict__ cIdx, const float* __restrict__ cVal,
    const int* __restrict__ cnt, uint2* __restrict__ pairsA) {
  const int idx = blockIdx.x * 256 + threadIdx.x;  // 0 .. 4096*68-1
  const int j = idx / PSTR;
  const int e = idx - j * PSTR;
  uint2 pr;
  if (e < cnt[j]) {                                // cnt <= MAXE < PSTR
    pr.x = (u32)cIdx[(size_t)j * MAXE + e] << 16;  // k * 16384 rows * 4B
    pr.y = __float_as_uint(cVal[(size_t)j * MAXE + e]);
  } else {
    pr.x = 0u; pr.y = 0u;                          // exact fold no-op / guard
  }
  pairsA[(size_t)j * PSTR + e] = pr;
}

// ---------- transpose: x[B][K] -> xTg[K][B] ----------
__global__ __launch_bounds__(256) void transpose_kernel(
    const float* __restrict__ x, float* __restrict__ xTg) {
  __shared__ float t[64][65];
  const int lane = threadIdx.x & 63;
  const int quad = threadIdx.x >> 6;               // 0..3
  const int kb = (blockIdx.x & 7) * 64;            // 8 k-tiles
  const int rb = (blockIdx.x >> 3) * 64;           // 256 row-tiles
#pragma unroll
  for (int i = 0; i < 16; ++i) {
    const int r = quad * 16 + i;
    t[lane][r] = x[(size_t)(rb + r) * K_DIM + kb + lane];  // coalesced read
  }
  __syncthreads();
#pragma unroll
  for (int i = 0; i < 16; ++i) {
    const int kq = quad * 16 + i;
    xTg[(size_t)(kb + kq) * BATCH + rb + lane] = t[kq][lane]; // coalesced write
  }
}

// ---------- fold v8: 64-row blocks, pipelined scalar pairs, global gather ----------
__global__ __launch_bounds__(1024, 4) void fold_kernel(
    const float* __restrict__ xTg, const uint2* __restrict__ pairsA,
    const int* __restrict__ cm4, float* __restrict__ y) {
  const int tid = threadIdx.x;
  const int lane = tid & 63;
  const int wave = __builtin_amdgcn_readfirstlane(tid >> 6);  // 0..15 uniform
  const int row0 = blockIdx.x * ROWS_A;
  const char* xb = (const char*)(xTg + row0) + (lane << 2);  // + e.x bytes

  const int jbase = wave * 256;                    // 256 cols per wave

#pragma unroll 1
  for (int g = 0; g < 8; ++g) {                    // 8 groups of 32 cols
    float acc[32];
#pragma unroll
    for (int q = 0; q < 32; ++q) acc[q] = 0.0f;

#pragma unroll
    for (int sub = 0; sub < 8; ++sub) {            // static: 8 subgrp x 4 cols
      const int j0 = jbase + g * 32 + sub * 4;     // uniform
      const int nchunk = cm4[j0 >> 2] >> 2;        // uniform s_load; chunks
      const chunk4* q0 = (const chunk4*)(pairsA + (size_t)(j0 + 0) * PSTR);
      const chunk4* q1 = (const chunk4*)(pairsA + (size_t)(j0 + 1) * PSTR);
      const chunk4* q2 = (const chunk4*)(pairsA + (size_t)(j0 + 2) * PSTR);
      const chunk4* q3 = (const chunk4*)(pairsA + (size_t)(j0 + 3) * PSTR);
      float a0 = 0.0f, a1 = 0.0f, a2 = 0.0f, a3 = 0.0f;
      chunk4 c0 = q0[0], c1 = q1[0], c2 = q2[0], c3 = q3[0];
#pragma unroll 1
      for (int ci = 0; ci < nchunk; ++ci) {
        // prefetch next chunk (guard row: index nchunk <= 16, stride 68)
        const chunk4 n0 = q0[ci + 1];
        const chunk4 n1 = q1[ci + 1];
        const chunk4 n2 = q2[ci + 1];
        const chunk4 n3 = q3[ci + 1];
#pragma unroll
        for (int q = 0; q < 4; ++q) {              // 16 gathers in flight
          const float x0 = *(const float*)(xb + c0.e[q].x);  // L2-hot
          const float x1 = *(const float*)(xb + c1.e[q].x);
          const float x2 = *(const float*)(xb + c2.e[q].x);
          const float x3 = *(const float*)(xb + c3.e[q].x);
          a0 = fmaf(__uint_as_float(c0.e[q].y), x0, a0);  // ascending-k fold
          a1 = fmaf(__uint_as_float(c1.e[q].y), x1, a1);
          a2 = fmaf(__uint_as_float(c2.e[q].y), x2, a2);
          a3 = fmaf(__uint_as_float(c3.e[q].y), x3, a3);
        }
        c0 = n0; c1 = n1; c2 = n2; c3 = n3;
      }
      acc[sub * 4 + 0] = a0;
      acc[sub * 4 + 1] = a1;
      acc[sub * 4 + 2] = a2;
      acc[sub * 4 + 3] = a3;
    }

    // 128B contiguous per lane (= per row) -> full HBM granules
    float* yp = y + (size_t)(row0 + lane) * N_DIM + jbase + g * 32;
#pragma unroll
    for (int q = 0; q < 8; ++q)
      *(f32x4*)(yp + q * 4) =
          (f32x4){acc[q * 4], acc[q * 4 + 1], acc[q * 4 + 2], acc[q * 4 + 3]};
  }
}

// ---------- select v5.1: contiguous in-place, 4-chain ballot search ----------
__global__ __launch_bounds__(256) void select_kernel(
    const float* __restrict__ bvec, const float* __restrict__ boost,
    const int* __restrict__ kptr, float* __restrict__ out) {
  const int lane = threadIdx.x & 63;
  const int row = blockIdx.x * 4 + (threadIdx.x >> 6);
  const u32 kk = (u32)kptr[0];
  float* orow = out + (size_t)row * N_DIM;

  u32 kv[64];
#pragma unroll
  for (int v = 0; v < 16; ++v) {
    const int j = v * 256 + lane * 4;              // f32x4, coalesced
    const f32x4 a = *(const f32x4*)(orow + j);
    const f32x4 b = *(const f32x4*)(bvec + j);
    const f32x4 gv = *(const f32x4*)(boost + j);
#pragma unroll
    for (int q = 0; q < 4; ++q) {
      const float yy = a[q] + b[q];                // single f32 add
      const u32 u = __float_as_uint(yy * gv[q]);   // single f32 mult
      kv[v * 4 + q] = (u & 0x80000000u) ? ~u : (u | 0x80000000u);
    }
  }

  // exact k-th-largest key: P = max C with count(key >= C) >= k (ties >=)
  u32 P = 0u;
#pragma unroll 1
  for (int bit = 31; bit >= 0; --bit) {
    const u32 C = P | (1u << bit);
    u32 c0 = 0u, c1 = 0u, c2 = 0u, c3 = 0u;       // 4 indep chains
#pragma unroll
    for (int s = 0; s < 16; ++s) {
      c0 += (u32)__popcll(__ballot(kv[s] >= C));
      c1 += (u32)__popcll(__ballot(kv[s + 16] >= C));
      c2 += (u32)__popcll(__ballot(kv[s + 32] >= C));
      c3 += (u32)__popcll(__ballot(kv[s + 48] >= C));
    }
    const u32 cc = (c0 + c1) + (c2 + c3);
    if (cc >= kk) P = C;                           // uniform
  }

  // re-read (L2-hot), recompute bit-identically, contiguous store
#pragma unroll
  for (int v = 0; v < 16; ++v) {
    const int j = v * 256 + lane * 4;
    const f32x4 a = *(const f32x4*)(orow + j);
    const f32x4 b = *(const f32x4*)(bvec + j);
    const f32x4 gv = *(const f32x4*)(boost + j);
    f32x4 o;
#pragma unroll
    for (int q = 0; q < 4; ++q) {
      const float yy = a[q] + b[q];
      const u32 u = __float_as_uint(yy * gv[q]);
      const u32 key = (u & 0x80000000u) ? ~u : (u | 0x80000000u);
      o[q] = (key >= P) ? yy : 0.0f;
    }
    *(f32x4*)(orow + j) = o;
  }
}

extern "C" void kernel_launch(void* const* d_in, const int* in_sizes, int n_in,
                              void* d_out, int out_size, void* d_ws, size_t ws_size,
                              hipStream_t stream) {
  const float* x     = (const float*)d_in[0];
  const float* W     = (const float*)d_in[1];
  const float* bvec  = (const float*)d_in[2];
  const float* wmask = (const float*)d_in[3];
  const float* duty  = (const float*)d_in[4];
  const int* kptr    = (const int*)d_in[5];
  float* out = (float*)d_out;

  uint8_t* ws = (uint8_t*)d_ws;
  unsigned short* cIdx = (unsigned short*)(ws);                 // 512 KiB
  float* cVal          = (float*)(ws + (1u << 20));             // 1 MiB
  int* cnt             = (int*)(ws + (2u << 20));               // 16 KiB
  float* boost         = (float*)(ws + (2u << 20) + (64u << 10));
  int* cm4             = (int*)(ws + (2u << 20) + (128u << 10)); // 4 KiB
  uint2* pairsA        = (uint2*)(ws + (4u << 20));             // 2.23 MiB
  float* xTg           = (float*)(ws + (8u << 20));             // 32 MiB
  // ws_size >= 42MB verified on-device (r16 fold_g path executed).

  boost_kernel<<<16, 256, 0, stream>>>(duty, kptr, boost);
  compress_kernel<<<N_DIM / 4, 256, 0, stream>>>(W, wmask, cIdx, cVal, cnt);
  cmax_kernel<<<4, 256, 0, stream>>>(cnt, cm4);
  fillA_kernel<<<(N_DIM * PSTR) / 256, 256, 0, stream>>>(cIdx, cVal, cnt, pairsA);
  transpose_kernel<<<2048, 256, 0, stream>>>(x, xTg);
  fold_kernel<<<BATCH / ROWS_A, 1024, 0, stream>>>(xTg, pairsA, cm4, out);
  select_kernel<<<BATCH / 4, 256, 0, stream>>>(bvec, boost, kptr, out);
}